// Round 1
// baseline (441.292 us; speedup 1.0000x reference)
//
#include <hip/hip_runtime.h>
#include <math.h>

#define HH 352
#define WW 352
constexpr float INFV = 1e10f;   // reference's stand-in for +inf

// ---------------------------------------------------------------------------
// Kernel 1: exact 1D squared-EDT along H (columns) for both fg and bg maps.
// For binary input, pass-1 of the min-plus EDT reduces to "squared distance to
// nearest nonzero (resp. zero) along the column", computable in two sweeps.
// Matches reference values exactly (integers are exact in f32; no-hit => 1e10).
// Also initializes the per-sample min/max atomics.
// ---------------------------------------------------------------------------
__global__ void col_pass_kernel(const float* __restrict__ target,
                                float* __restrict__ Ffg, float* __restrict__ Fbg,
                                unsigned int* __restrict__ mm, int B)
{
    if (blockIdx.x == 0) {
        for (int k = threadIdx.x; k < 2 * B; k += blockDim.x)
            mm[k] = (k & 1) ? 0u : 0x7f800000u;   // max init = 0, min init = +inf
    }
    int tid = blockIdx.x * blockDim.x + threadIdx.x;
    int ncol = B * WW;
    if (tid >= ncol) return;
    int b = tid / WW;
    int j = tid - b * WW;
    const size_t cb = (size_t)b * HH * WW + j;
    const float* tcol = target + cb;
    float* fF = Ffg + cb;
    float* fB = Fbg + cb;

    int lastF = -1, lastB = -1;
    for (int i = 0; i < HH; ++i) {
        float tv = tcol[(size_t)i * WW];
        if (tv != 0.0f) lastF = i; else lastB = i;
        float vF, vB;
        if (lastF < 0) vF = INFV; else { int d = i - lastF; vF = (float)(d * d); }
        if (lastB < 0) vB = INFV; else { int d = i - lastB; vB = (float)(d * d); }
        fF[(size_t)i * WW] = vF;
        fB[(size_t)i * WW] = vB;
    }
    int nextF = -1, nextB = -1;
    for (int i = HH - 1; i >= 0; --i) {
        float tv = tcol[(size_t)i * WW];
        if (tv != 0.0f) nextF = i; else nextB = i;
        if (nextF >= 0) {
            int d = nextF - i; float v = (float)(d * d);
            size_t o = (size_t)i * WW;
            if (v < fF[o]) fF[o] = v;
        }
        if (nextB >= 0) {
            int d = nextB - i; float v = (float)(d * d);
            size_t o = (size_t)i * WW;
            if (v < fB[o]) fB[o] = v;
        }
    }
}

// ---------------------------------------------------------------------------
// Kernel 2: min-plus pass along W for both maps (exact, brute force O(W^2)
// per row — same arithmetic as reference: min_j' g[j'] + (j-j')^2 in f32),
// then sdt / w, plus per-sample min/max via positive-float-as-uint atomics.
// One block per row; row staged in LDS (lockstep broadcast reads).
// ---------------------------------------------------------------------------
__global__ __launch_bounds__(128) void row_pass_kernel(const float* __restrict__ Ffg,
                                                       const float* __restrict__ Fbg,
                                                       float* __restrict__ Wm,
                                                       unsigned int* __restrict__ mm)
{
    int blk = blockIdx.x;
    int b = blk / HH;
    int i = blk - b * HH;
    const size_t base = ((size_t)b * HH + i) * WW;

    __shared__ float sF[WW];
    __shared__ float sB[WW];
    for (int idx = threadIdx.x; idx < WW; idx += 128) {
        sF[idx] = Ffg[base + idx];
        sB[idx] = Fbg[base + idx];
    }
    __syncthreads();

    float lmin = INFINITY, lmax = 0.0f;
    for (int j = threadIdx.x; j < WW; j += 128) {
        float dF = 3e38f, dB = 3e38f;
        #pragma unroll 4
        for (int jp = 0; jp < WW; ++jp) {
            int d = j - jp;
            float sq = (float)(d * d);
            dF = fminf(dF, sF[jp] + sq);
            dB = fminf(dB, sB[jp] + sq);
        }
        float sdt = sqrtf(dB) - sqrtf(dF);
        float w = expf(-fabsf(sdt) * 0.2f);   // SIGMA = 5
        Wm[base + j] = w;
        lmin = fminf(lmin, w);
        lmax = fmaxf(lmax, w);
    }

    __shared__ float smin[128];
    __shared__ float smax[128];
    smin[threadIdx.x] = lmin;
    smax[threadIdx.x] = lmax;
    __syncthreads();
    for (int s = 64; s > 0; s >>= 1) {
        if (threadIdx.x < s) {
            smin[threadIdx.x] = fminf(smin[threadIdx.x], smin[threadIdx.x + s]);
            smax[threadIdx.x] = fmaxf(smax[threadIdx.x], smax[threadIdx.x + s]);
        }
        __syncthreads();
    }
    if (threadIdx.x == 0) {
        // w > 0 so float ordering == uint ordering on the raw bits
        atomicMin(&mm[2 * b],     __float_as_uint(smin[0]));
        atomicMax(&mm[2 * b + 1], __float_as_uint(smax[0]));
    }
}

// ---------------------------------------------------------------------------
// Kernel 3: BCE-with-logits * (1 + 0.5 * normalized w); per-block partial sums.
// N = 495616 = 1936 * 256; per-sample pixel count 123904 = 484 * 256, so each
// block lies entirely within one sample (b is block-uniform).
// ---------------------------------------------------------------------------
__global__ __launch_bounds__(256) void loss_kernel(const float* __restrict__ pred,
                                                   const float* __restrict__ target,
                                                   const float* __restrict__ Wm,
                                                   const unsigned int* __restrict__ mm,
                                                   float* __restrict__ partials)
{
    const int HW = HH * WW;
    int idx = blockIdx.x * 256 + threadIdx.x;
    int b = idx / HW;
    float wmin = __uint_as_float(mm[2 * b]);
    float wmax = __uint_as_float(mm[2 * b + 1]);
    float p = pred[idx];
    float t = target[idx];
    float w = Wm[idx];
    float wn = (w - wmin) / (wmax - wmin + 1e-6f);
    float bce = fmaxf(p, 0.0f) - p * t + log1pf(expf(-fabsf(p)));
    float v = bce * (1.0f + 0.5f * wn);

    __shared__ float ssum[256];
    ssum[threadIdx.x] = v;
    __syncthreads();
    for (int s = 128; s > 0; s >>= 1) {
        if (threadIdx.x < s) ssum[threadIdx.x] += ssum[threadIdx.x + s];
        __syncthreads();
    }
    if (threadIdx.x == 0) partials[blockIdx.x] = ssum[0];
}

// ---------------------------------------------------------------------------
// Kernel 4: final reduction (double accumulation) -> mean -> d_out[0]
// ---------------------------------------------------------------------------
__global__ __launch_bounds__(256) void final_kernel(const float* __restrict__ partials,
                                                    float* __restrict__ out,
                                                    int nPart, double invN)
{
    __shared__ double s[256];
    double acc = 0.0;
    for (int i = threadIdx.x; i < nPart; i += 256) acc += (double)partials[i];
    s[threadIdx.x] = acc;
    __syncthreads();
    for (int st = 128; st > 0; st >>= 1) {
        if (threadIdx.x < st) s[threadIdx.x] += s[threadIdx.x + st];
        __syncthreads();
    }
    if (threadIdx.x == 0) out[0] = (float)(s[0] * invN);
}

extern "C" void kernel_launch(void* const* d_in, const int* in_sizes, int n_in,
                              void* d_out, int out_size, void* d_ws, size_t ws_size,
                              hipStream_t stream)
{
    const float* pred   = (const float*)d_in[0];
    const float* target = (const float*)d_in[1];
    float* out = (float*)d_out;

    const int N = in_sizes[0];           // B*1*H*W
    const int B = N / (HH * WW);         // = 4

    float* Ffg = (float*)d_ws;
    float* Fbg = Ffg + N;
    float* Wm  = Fbg + N;
    unsigned int* mm = (unsigned int*)(Wm + N);
    float* partials  = (float*)(mm + 2 * B);

    // 1) column EDT pass (both maps) + minmax init
    int ncol = B * WW;
    int blocks1 = (ncol + 255) / 256;
    hipLaunchKernelGGL(col_pass_kernel, dim3(blocks1), dim3(256), 0, stream,
                       target, Ffg, Fbg, mm, B);

    // 2) row min-plus pass + w + per-sample min/max
    hipLaunchKernelGGL(row_pass_kernel, dim3(B * HH), dim3(128), 0, stream,
                       Ffg, Fbg, Wm, mm);

    // 3) weighted BCE partial sums
    int nPart = N / 256;
    hipLaunchKernelGGL(loss_kernel, dim3(nPart), dim3(256), 0, stream,
                       pred, target, Wm, mm, partials);

    // 4) final mean
    hipLaunchKernelGGL(final_kernel, dim3(1), dim3(256), 0, stream,
                       partials, out, nPart, 1.0 / (double)N);
}

// Round 2
// 162.804 us; speedup vs baseline: 2.7106x; 2.7106x over previous
//
#include <hip/hip_runtime.h>
#include <math.h>

#define HH 352
#define WW 352
constexpr float INFV = 1e10f;   // reference's stand-in for +inf

// ---------------------------------------------------------------------------
// Kernel 1: exact 1D min-plus squared-EDT along H (columns) for both maps.
// One block per column (B*W blocks). Column's g-values (0 or 1e10) staged in
// LDS; each thread brute-forces min_{i'} g[i'] + (i-i')^2 — bit-identical to
// the reference's pass 1. Block 0 also initializes the per-sample min/max.
// ---------------------------------------------------------------------------
__global__ __launch_bounds__(128) void col_pass_kernel(const float* __restrict__ target,
                                                       float* __restrict__ Ffg,
                                                       float* __restrict__ Fbg,
                                                       unsigned int* __restrict__ mm, int B)
{
    if (blockIdx.x == 0) {
        for (int k = threadIdx.x; k < 2 * B; k += 128)
            mm[k] = (k & 1) ? 0u : 0x7f800000u;   // min init = +inf, max init = 0
    }
    int blk = blockIdx.x;
    int b = blk / WW;
    int j = blk - b * WW;
    const size_t cb = (size_t)b * HH * WW + j;   // column base: element (b, i=0, j)

    __shared__ float sGF[HH];
    __shared__ float sGB[HH];
    for (int i = threadIdx.x; i < HH; i += 128) {
        float tv = target[cb + (size_t)i * WW];
        bool fg = (tv != 0.0f);
        sGF[i] = fg ? INFV : 0.0f;   // g for distance-to-zero-of(~mask) = dist_fg
        sGB[i] = fg ? 0.0f : INFV;   // g for dist_bg
    }
    __syncthreads();

    for (int i = threadIdx.x; i < HH; i += 128) {
        float dF = 3e38f, dB = 3e38f;
        #pragma unroll 4
        for (int ip = 0; ip < HH; ++ip) {
            int d = i - ip;
            float sq = (float)(d * d);
            dF = fminf(dF, sGF[ip] + sq);
            dB = fminf(dB, sGB[ip] + sq);
        }
        size_t o = cb + (size_t)i * WW;
        Ffg[o] = dF;
        Fbg[o] = dB;
    }
}

// ---------------------------------------------------------------------------
// Kernel 2: min-plus pass along W for both maps (exact, brute force O(W^2)
// per row — same arithmetic as reference), then sdt / w, plus per-sample
// min/max via positive-float-as-uint atomics. One block per row.
// ---------------------------------------------------------------------------
__global__ __launch_bounds__(128) void row_pass_kernel(const float* __restrict__ Ffg,
                                                       const float* __restrict__ Fbg,
                                                       float* __restrict__ Wm,
                                                       unsigned int* __restrict__ mm)
{
    int blk = blockIdx.x;
    int b = blk / HH;
    int i = blk - b * HH;
    const size_t base = ((size_t)b * HH + i) * WW;

    __shared__ float sF[WW];
    __shared__ float sB[WW];
    for (int idx = threadIdx.x; idx < WW; idx += 128) {
        sF[idx] = Ffg[base + idx];
        sB[idx] = Fbg[base + idx];
    }
    __syncthreads();

    float lmin = INFINITY, lmax = 0.0f;
    for (int j = threadIdx.x; j < WW; j += 128) {
        float dF = 3e38f, dB = 3e38f;
        #pragma unroll 4
        for (int jp = 0; jp < WW; ++jp) {
            int d = j - jp;
            float sq = (float)(d * d);
            dF = fminf(dF, sF[jp] + sq);
            dB = fminf(dB, sB[jp] + sq);
        }
        float sdt = sqrtf(dB) - sqrtf(dF);
        float w = expf(-fabsf(sdt) * 0.2f);   // SIGMA = 5
        Wm[base + j] = w;
        lmin = fminf(lmin, w);
        lmax = fmaxf(lmax, w);
    }

    __shared__ float smin[128];
    __shared__ float smax[128];
    smin[threadIdx.x] = lmin;
    smax[threadIdx.x] = lmax;
    __syncthreads();
    for (int s = 64; s > 0; s >>= 1) {
        if (threadIdx.x < s) {
            smin[threadIdx.x] = fminf(smin[threadIdx.x], smin[threadIdx.x + s]);
            smax[threadIdx.x] = fmaxf(smax[threadIdx.x], smax[threadIdx.x + s]);
        }
        __syncthreads();
    }
    if (threadIdx.x == 0) {
        // w > 0 so float ordering == uint ordering on the raw bits
        atomicMin(&mm[2 * b],     __float_as_uint(smin[0]));
        atomicMax(&mm[2 * b + 1], __float_as_uint(smax[0]));
    }
}

// ---------------------------------------------------------------------------
// Kernel 3: BCE-with-logits * (1 + 0.5 * normalized w); per-block partial sums.
// N = 495616 = 1936 * 256; per-sample pixel count 123904 is a multiple of 256,
// so each block lies entirely within one sample (b is block-uniform).
// ---------------------------------------------------------------------------
__global__ __launch_bounds__(256) void loss_kernel(const float* __restrict__ pred,
                                                   const float* __restrict__ target,
                                                   const float* __restrict__ Wm,
                                                   const unsigned int* __restrict__ mm,
                                                   float* __restrict__ partials)
{
    const int HW = HH * WW;
    int idx = blockIdx.x * 256 + threadIdx.x;
    int b = idx / HW;
    float wmin = __uint_as_float(mm[2 * b]);
    float wmax = __uint_as_float(mm[2 * b + 1]);
    float p = pred[idx];
    float t = target[idx];
    float w = Wm[idx];
    float wn = (w - wmin) / (wmax - wmin + 1e-6f);
    float bce = fmaxf(p, 0.0f) - p * t + log1pf(expf(-fabsf(p)));
    float v = bce * (1.0f + 0.5f * wn);

    __shared__ float ssum[256];
    ssum[threadIdx.x] = v;
    __syncthreads();
    for (int s = 128; s > 0; s >>= 1) {
        if (threadIdx.x < s) ssum[threadIdx.x] += ssum[threadIdx.x + s];
        __syncthreads();
    }
    if (threadIdx.x == 0) partials[blockIdx.x] = ssum[0];
}

// ---------------------------------------------------------------------------
// Kernel 4: final reduction (double accumulation) -> mean -> d_out[0]
// ---------------------------------------------------------------------------
__global__ __launch_bounds__(256) void final_kernel(const float* __restrict__ partials,
                                                    float* __restrict__ out,
                                                    int nPart, double invN)
{
    __shared__ double s[256];
    double acc = 0.0;
    for (int i = threadIdx.x; i < nPart; i += 256) acc += (double)partials[i];
    s[threadIdx.x] = acc;
    __syncthreads();
    for (int st = 128; st > 0; st >>= 1) {
        if (threadIdx.x < st) s[threadIdx.x] += s[threadIdx.x + st];
        __syncthreads();
    }
    if (threadIdx.x == 0) out[0] = (float)(s[0] * invN);
}

extern "C" void kernel_launch(void* const* d_in, const int* in_sizes, int n_in,
                              void* d_out, int out_size, void* d_ws, size_t ws_size,
                              hipStream_t stream)
{
    const float* pred   = (const float*)d_in[0];
    const float* target = (const float*)d_in[1];
    float* out = (float*)d_out;

    const int N = in_sizes[0];           // B*1*H*W
    const int B = N / (HH * WW);         // = 4

    float* Ffg = (float*)d_ws;
    float* Fbg = Ffg + N;
    float* Wm  = Fbg + N;
    unsigned int* mm = (unsigned int*)(Wm + N);
    float* partials  = (float*)(mm + 2 * B);

    // 1) column min-plus pass (both maps) + minmax init — one block per column
    hipLaunchKernelGGL(col_pass_kernel, dim3(B * WW), dim3(128), 0, stream,
                       target, Ffg, Fbg, mm, B);

    // 2) row min-plus pass + w + per-sample min/max — one block per row
    hipLaunchKernelGGL(row_pass_kernel, dim3(B * HH), dim3(128), 0, stream,
                       Ffg, Fbg, Wm, mm);

    // 3) weighted BCE partial sums
    int nPart = N / 256;
    hipLaunchKernelGGL(loss_kernel, dim3(nPart), dim3(256), 0, stream,
                       pred, target, Wm, mm, partials);

    // 4) final mean
    hipLaunchKernelGGL(final_kernel, dim3(1), dim3(256), 0, stream,
                       partials, out, nPart, 1.0 / (double)N);
}

// Round 5
// 118.758 us; speedup vs baseline: 3.7159x; 1.3709x over previous
//
#include <hip/hip_runtime.h>
#include <math.h>

#define HH 352
#define WW 352
constexpr float INFV = 1e10f;   // reference's stand-in for +inf

// ---------------------------------------------------------------------------
// Kernel 1: column pass, one THREAD per pixel. For binary input, the 1D
// min-plus EDT along the column equals (dist to nearest opposite pixel)^2,
// found by outward scan (expected ~2-3 steps for random data; exact for any
// input, sentinel 1e10 if no opposite exists in the column).
//   gF = 0 at fg pixels else dist-to-nearest-fg^2; gB symmetric.
// All finite values are exact integers < 2^24 -> bit-exact vs reference f32.
// ---------------------------------------------------------------------------
__global__ __launch_bounds__(256) void col_win_kernel(const float* __restrict__ target,
                                                      float* __restrict__ gF,
                                                      float* __restrict__ gB,
                                                      unsigned int* __restrict__ mm, int B)
{
    int idx = blockIdx.x * 256 + threadIdx.x;
    if (blockIdx.x == 0 && threadIdx.x < 2 * B)
        mm[threadIdx.x] = (threadIdx.x & 1) ? 0u : 0x7f800000u;  // min=+inf, max=0

    const int HW = HH * WW;
    int b = idx / HW;
    int r = idx - b * HW;
    int i = r / WW;                    // row within image

    float tv = target[idx];
    bool fg = (tv != 0.0f);

    float dsq = INFV;                  // squared col-distance to nearest opposite
    for (int k = 1; k < HH; ++k) {
        int iu = i - k, id = i + k;
        bool hit = false;
        if (iu >= 0) {
            float v = target[idx - k * WW];
            hit = ((v != 0.0f) != fg);
        }
        if (!hit && id < HH) {
            float v = target[idx + k * WW];
            hit = ((v != 0.0f) != fg);
        }
        if (hit) { dsq = (float)(k * k); break; }
        if (iu < 0 && id >= HH) break;
    }
    gF[idx] = fg ? 0.0f : dsq;
    gB[idx] = fg ? dsq : 0.0f;
}

// ---------------------------------------------------------------------------
// Kernel 2: row min-plus pass, one THREAD per pixel, exact windowed search:
//   best = g[j] (k=0); candidates at distance k only matter while k^2 < best.
// Exact: all finite terms are integers < 2^24 (f32-exact); g >= 0 so the stop
// rule is safe. Then sdt -> w -> store + per-sample min/max atomics.
// ---------------------------------------------------------------------------
__global__ __launch_bounds__(256) void row_win_kernel(const float* __restrict__ gF,
                                                      const float* __restrict__ gB,
                                                      float* __restrict__ Wm,
                                                      unsigned int* __restrict__ mm)
{
    const int HW = HH * WW;
    int idx = blockIdx.x * 256 + threadIdx.x;
    int b = idx / HW;
    int r = idx - b * HW;
    int i = r / WW;
    int j = r - i * WW;

    float bF = gF[idx];
    float bB = gB[idx];
    for (int k = 1; k < WW; ++k) {
        float sq = (float)(k * k);
        if (sq >= bF && sq >= bB) break;          // no candidate can improve
        int jl = j - k, jr = j + k;
        if (jl >= 0) {
            bF = fminf(bF, gF[idx - k] + sq);
            bB = fminf(bB, gB[idx - k] + sq);
        }
        if (jr < WW) {
            bF = fminf(bF, gF[idx + k] + sq);
            bB = fminf(bB, gB[idx + k] + sq);
        }
        if (jl < 0 && jr >= WW) break;
    }

    float sdt = sqrtf(bB) - sqrtf(bF);            // sign irrelevant: |sdt| below
    float w = expf(-fabsf(sdt) * 0.2f);           // SIGMA = 5
    Wm[idx] = w;

    // block-level min/max reduce (b is uniform per block: HW % 256 == 0)
    __shared__ float smin[256];
    __shared__ float smax[256];
    smin[threadIdx.x] = w;
    smax[threadIdx.x] = w;
    __syncthreads();
    for (int s = 128; s > 0; s >>= 1) {
        if (threadIdx.x < s) {
            smin[threadIdx.x] = fminf(smin[threadIdx.x], smin[threadIdx.x + s]);
            smax[threadIdx.x] = fmaxf(smax[threadIdx.x], smax[threadIdx.x + s]);
        }
        __syncthreads();
    }
    if (threadIdx.x == 0) {
        // w > 0 so float ordering == uint ordering on the raw bits
        atomicMin(&mm[2 * b],     __float_as_uint(smin[0]));
        atomicMax(&mm[2 * b + 1], __float_as_uint(smax[0]));
    }
}

// ---------------------------------------------------------------------------
// Kernel 3: BCE-with-logits * (1 + 0.5 * normalized w); per-block partial sums.
// ---------------------------------------------------------------------------
__global__ __launch_bounds__(256) void loss_kernel(const float* __restrict__ pred,
                                                   const float* __restrict__ target,
                                                   const float* __restrict__ Wm,
                                                   const unsigned int* __restrict__ mm,
                                                   float* __restrict__ partials)
{
    const int HW = HH * WW;
    int idx = blockIdx.x * 256 + threadIdx.x;
    int b = idx / HW;
    float wmin = __uint_as_float(mm[2 * b]);
    float wmax = __uint_as_float(mm[2 * b + 1]);
    float p = pred[idx];
    float t = target[idx];
    float w = Wm[idx];
    float wn = (w - wmin) / (wmax - wmin + 1e-6f);
    float bce = fmaxf(p, 0.0f) - p * t + log1pf(expf(-fabsf(p)));
    float v = bce * (1.0f + 0.5f * wn);

    __shared__ float ssum[256];
    ssum[threadIdx.x] = v;
    __syncthreads();
    for (int s = 128; s > 0; s >>= 1) {
        if (threadIdx.x < s) ssum[threadIdx.x] += ssum[threadIdx.x + s];
        __syncthreads();
    }
    if (threadIdx.x == 0) partials[blockIdx.x] = ssum[0];
}

// ---------------------------------------------------------------------------
// Kernel 4: final reduction (double accumulation) -> mean -> d_out[0]
// ---------------------------------------------------------------------------
__global__ __launch_bounds__(256) void final_kernel(const float* __restrict__ partials,
                                                    float* __restrict__ out,
                                                    int nPart, double invN)
{
    __shared__ double s[256];
    double acc = 0.0;
    for (int i = threadIdx.x; i < nPart; i += 256) acc += (double)partials[i];
    s[threadIdx.x] = acc;
    __syncthreads();
    for (int st = 128; st > 0; st >>= 1) {
        if (threadIdx.x < st) s[threadIdx.x] += s[threadIdx.x + st];
        __syncthreads();
    }
    if (threadIdx.x == 0) out[0] = (float)(s[0] * invN);
}

extern "C" void kernel_launch(void* const* d_in, const int* in_sizes, int n_in,
                              void* d_out, int out_size, void* d_ws, size_t ws_size,
                              hipStream_t stream)
{
    const float* pred   = (const float*)d_in[0];
    const float* target = (const float*)d_in[1];
    float* out = (float*)d_out;

    const int N = in_sizes[0];           // B*1*H*W
    const int B = N / (HH * WW);         // = 4

    float* gF = (float*)d_ws;
    float* gB = gF + N;
    float* Wm = gB + N;
    unsigned int* mm = (unsigned int*)(Wm + N);
    float* partials  = (float*)(mm + 2 * B);

    int nBlk = N / 256;                  // 1936, exact

    // 1) column windowed EDT pass (both maps) + minmax init
    hipLaunchKernelGGL(col_win_kernel, dim3(nBlk), dim3(256), 0, stream,
                       target, gF, gB, mm, B);

    // 2) row windowed min-plus pass + w + per-sample min/max
    hipLaunchKernelGGL(row_win_kernel, dim3(nBlk), dim3(256), 0, stream,
                       gF, gB, Wm, mm);

    // 3) weighted BCE partial sums
    hipLaunchKernelGGL(loss_kernel, dim3(nBlk), dim3(256), 0, stream,
                       pred, target, Wm, mm, partials);

    // 4) final mean
    hipLaunchKernelGGL(final_kernel, dim3(1), dim3(256), 0, stream,
                       partials, out, nBlk, 1.0 / (double)N);
}